// Round 9
// baseline (429.518 us; speedup 1.0000x reference)
//
#include <hip/hip_runtime.h>
#include <math.h>

typedef unsigned long long u64;

static constexpr int S    = 771;   // NB_LABELS*MAX_DEPTH + EXTRA
static constexpr int Tn   = 128;
static constexpr int Bn   = 32;
static constexpr int BOSs = 0;
static constexpr int EOSs = 1;

static constexpr int JPAD  = 832;          // 13 * 64 state pad
static constexpr int JB    = 13;           // state-blocks per batch
static constexpr int ROWS  = 64;           // output rows per block (= lanes)
static constexpr int NQ    = 4;            // inner K-quarters (= waves)
static constexpr int SL    = JPAD / NQ;    // 208 i8 inner slice per thread
static constexpr int CH    = SL / 16;      // 13 x b128 per thread
static constexpr int EBLK  = NQ * CH * ROWS * 16;    // 53248 B per jblk
static constexpr int ETOT  = JB * EBLK;              // 692224 B
static constexpr int NG    = JB * 17;      // 221 u64 per (batch,step)
static constexpr int XSTR  = 224;          // padded stride (u64) per (parity,batch)
static constexpr float CB  = 8.0f;         // normalizer headroom (drift bound)
static constexpr float C0V = 4.5f;         // fixed normalizer for t=0 publish

__device__ __forceinline__ float wave_max_bfly(float v) {   // result in ALL lanes
    #pragma unroll
    for (int off = 32; off > 0; off >>= 1) v = fmaxf(v, __shfl_xor(v, off));
    return v;
}
__device__ __forceinline__ float wave_sum_f(float v) {
    #pragma unroll
    for (int off = 32; off > 0; off >>= 1) v += __shfl_down(v, off);
    return v;
}

__device__ __forceinline__ u64 ald64(const u64* p) {
    return __hip_atomic_load((u64*)p, __ATOMIC_RELAXED, __HIP_MEMORY_SCOPE_AGENT);
}
__device__ __forceinline__ void ast64(u64* p, u64 v) {
    __hip_atomic_store(p, v, __ATOMIC_RELAXED, __HIP_MEMORY_SCOPE_AGENT);
}
__device__ __forceinline__ u64 pack(unsigned tag, unsigned payload) {
    return ((u64)tag << 32) | (u64)payload;
}

// i8 x i8 + i32 dot (both operands in [0,127], so signed == unsigned)
#if __has_builtin(__builtin_amdgcn_sdot4)
__device__ __forceinline__ int dot4i(unsigned a, unsigned b, int c) {
    return __builtin_amdgcn_sdot4((int)a, (int)b, c, false);
}
#else
__device__ __forceinline__ int dot4i(unsigned a, unsigned b, int c) {
    c += (int)(a & 0xff)         * (int)(b & 0xff);
    c += (int)((a >> 8) & 0xff)  * (int)((b >> 8) & 0xff);
    c += (int)((a >> 16) & 0xff) * (int)((b >> 16) & 0xff);
    c += (int)((a >> 24) & 0xff) * (int)((b >> 24) & 0xff);
    return c;
}
#endif

// ---------------------------------------------------------------------------
// Prep: i8 exp-transition table (swizzled, identical layout to r8) +
// exp(trans[:,EOS]) f32 column.
// eswz[jblk][q][kk][lane][16] = round(115*exp(trans[i][j])) in [0,127],
//   i = q*208 + kk*16 + e (inner), j = jblk*64 + lane (output row).
// ---------------------------------------------------------------------------
extern "C" __global__ void build_tabs(const float* __restrict__ trans,
                                      unsigned char* __restrict__ eswz,
                                      float* __restrict__ eteos) {
    int idx = blockIdx.x * blockDim.x + threadIdx.x;
    if (idx < JPAD)
        eteos[idx] = (idx < S) ? __expf(trans[idx * S + EOSs]) : 0.f;
    if (idx >= ETOT) return;
    int e = idx & 15;
    int q = idx >> 4;
    int lane = q & 63;  q >>= 6;
    int kk = q % 13;
    int h  = q / 13;
    int w  = h & 3, jblk = h >> 2;
    int i = w * SL + kk * 16 + e;
    int j = jblk * ROWS + lane;
    float v = 0.f;
    if (i < S && j < S) v = 115.f * __expf(trans[i * S + j]);
    int q8 = (int)(v + 0.5f);
    if (q8 > 127) q8 = 127;
    eswz[idx] = (unsigned char)q8;
}

// ---------------------------------------------------------------------------
// Gold-path scores (unchanged, passing since round 1).
// ---------------------------------------------------------------------------
extern "C" __global__ __launch_bounds__(Tn)
void crf_scores(const float* __restrict__ em, const int* __restrict__ tags,
                const float* __restrict__ mask, const float* __restrict__ trans,
                float* __restrict__ scores) {
    const int b = blockIdx.x, t = threadIdx.x;
    const int lane = t & 63, wid = t >> 6;
    __shared__ float redv[2], redm[2];

    float mk = mask[b * Tn + t];
    float val = 0.f;
    if (t > 0) {
        int cur  = tags[b * Tn + t];
        int prev = tags[b * Tn + t - 1];
        val = (em[((size_t)b * Tn + t) * S + cur] + trans[prev * S + cur]) * mk;
    }
    float v  = wave_sum_f(val);
    float ms = wave_sum_f(mk);
    if (lane == 0) { redv[wid] = v; redm[wid] = ms; }
    __syncthreads();
    if (t == 0) {
        float tot  = redv[0] + redv[1];
        float msum = redm[0] + redm[1];
        int last  = (int)(msum + 0.5f) - 1;
        int first = tags[b * Tn];
        int lastt = tags[b * Tn + last];
        scores[b] = tot + trans[BOSs * S + first]
                        + em[((size_t)b * Tn) * S + first]
                        + trans[lastt * S + EOSs];
    }
}

// publish (one wave): 64 rows -> p8 = round(127*exp(alpha-C)) packed 4/u64
// (16 u64) + 1 u64 f32 chunk max. Tag stream IS the sync.
__device__ __forceinline__ void publish(u64* W, int jblk, unsigned tag,
                                        float af, float C, int lane) {
    float xf = fminf(127.f, 127.f * __expf(af - C));   // -inf/-1e9 -> 0
    int xi = (int)(xf + 0.5f);
    int b0 = __shfl(xi, (4 * lane) & 63);
    int b1 = __shfl(xi, (4 * lane + 1) & 63);
    int b2 = __shfl(xi, (4 * lane + 2) & 63);
    int b3 = __shfl(xi, (4 * lane + 3) & 63);
    unsigned payload = (unsigned)b0 | ((unsigned)b1 << 8)
                     | ((unsigned)b2 << 16) | ((unsigned)b3 << 24);
    float mc = wave_max_bfly(af);
    u64* base = W + 17 * jblk;
    if (lane < 16)  ast64(base + lane, pack(tag, payload));
    if (lane == 16) ast64(base + 16,   pack(tag, __float_as_uint(mc)));
}

// ---------------------------------------------------------------------------
// Forward algorithm, r9: TWO batches per block -> grid 13 x 16 = 208 blocks
// <= 256 CUs => one block per CU (kills the r8 co-residency straggler:
// 416 blocks put 2 foreign-gang blocks on ~160 CUs; gang period = slowest
// member). Waves = 4 K-quarters; each thread reads its E b128 ONCE and dots
// it against both batches' p (acc0/acc1) -> E LDS traffic unchanged.
// Epilogue waves 0/1 serve batch 0/1 in parallel. Exchange protocol = r8.
// ---------------------------------------------------------------------------
extern "C" __global__ __launch_bounds__(256, 2)
void crf_fwd(const float* __restrict__ em, const float* __restrict__ mask,
             const float* __restrict__ trans, const unsigned char* __restrict__ eswz,
             const float* __restrict__ eteos, const float* __restrict__ scores,
             u64* __restrict__ xb, float* __restrict__ out) {
    const int jblk = blockIdx.x;
    const int b0 = blockIdx.y * 2, b1 = b0 + 1;
    const int tid = threadIdx.x, lane = tid & 63, w = tid >> 6;
    const int j0 = jblk * ROWS;

    __shared__ __align__(16) unsigned char Elds[EBLK];  // 52 KB i8 E tile
    __shared__ __align__(16) unsigned pbuf[2][SL];      // 2 x 832 p8
    __shared__ int   part[2][256];
    __shared__ float mch[2][16];
    __shared__ float reds[2][4];
    __shared__ float csh[2];

    const float KLOG  = __logf(115.f * 127.f);
    const float KL127 = __logf(127.f);

    // ---- one-time: stage this block's E tile (13 x 4KB linear copy) ----
    {
        const unsigned char* gsrc = eswz + (size_t)jblk * EBLK;
        #pragma unroll
        for (int it = 0; it < EBLK / 4096; ++it)
            *(float4*)(Elds + it * 4096 + tid * 16) =
                *(const float4*)(gsrc + it * 4096 + tid * 16);
    }

    // epilogue waves 0/1 own batch b0/b1; af = alpha of row j0+lane
    const int myb = (w == 1) ? b1 : b0;
    float af = -INFINITY, Cuse = C0V;

    if (w < 2) {
        int j = j0 + lane;
        if (j < S) af = trans[BOSs * S + j] + em[((size_t)myb * Tn + 0) * S + j];
        publish(xb + ((size_t)0 * Bn + myb) * XSTR, jblk, 0u, af, C0V, lane);
    }

    const bool act = (tid < NG);
    const int c17 = tid / 17, s17 = tid - c17 * 17;

    // ---- 127 sequential steps ----
    for (int t = 1; t < Tn; ++t) {
        const u64* R0 = xb + ((size_t)((t - 1) & 1) * Bn + b0) * XSTR;
        const u64* R1 = xb + ((size_t)((t - 1) & 1) * Bn + b1) * XSTR;
        u64*       W  = xb + ((size_t)((t    ) & 1) * Bn + myb) * XSTR;

        // epilogue operands independent of alpha: issue before the poll
        float emv = 0.f, mval = 0.f;
        if (w < 2) {
            const int j = j0 + lane;
            if (j < S) emv = em[((size_t)myb * Tn + t) * S + j];
            mval = mask[myb * Tn + t];
        }

        // ---- poll both tagged streams (2 u64, latencies overlap) ----
        const unsigned tg = (unsigned)(t - 1);
        u64 q0 = 0, q1 = 0;
        bool ok = !act;
        while (true) {
            if (!ok) {
                q0 = ald64(R0 + tid);
                q1 = ald64(R1 + tid);
                ok = ((unsigned)(q0 >> 32) == tg) & ((unsigned)(q1 >> 32) == tg);
            }
            if (__syncthreads_and(ok)) break;
        }

        // ---- unpack: packed p8 -> LDS; chunk maxes -> mch ----
        if (act) {
            if (s17 == 16) {
                mch[0][c17] = __uint_as_float((unsigned)q0);
                mch[1][c17] = __uint_as_float((unsigned)q1);
            } else {
                pbuf[0][c17 * 16 + s17] = (unsigned)q0;
                pbuf[1][c17 * 16 + s17] = (unsigned)q1;
            }
        }
        __syncthreads();

        // epilogue waves: next normalizer from own batch's chunk maxes
        float Cnew = 0.f;
        if (w < 2) {
            float mv = (lane < JB) ? mch[w][lane] : -INFINITY;
            Cnew = wave_max_bfly(mv) + CB;
        }

        // ---- dot: one E b128 read feeds BOTH batches' accumulators ----
        int acc0 = 0, acc1 = 0;
        const uint4* E4 = (const uint4*)Elds;
        const uint4* P0 = (const uint4*)pbuf[0];
        const uint4* P1 = (const uint4*)pbuf[1];
        #pragma unroll
        for (int kk = 0; kk < CH; ++kk) {
            const uint4 ev = E4[(w * CH + kk) * 64 + lane];
            const uint4 pa = P0[w * CH + kk];
            const uint4 pb = P1[w * CH + kk];
            acc0 = dot4i(ev.x, pa.x, acc0); acc0 = dot4i(ev.y, pa.y, acc0);
            acc0 = dot4i(ev.z, pa.z, acc0); acc0 = dot4i(ev.w, pa.w, acc0);
            acc1 = dot4i(ev.x, pb.x, acc1); acc1 = dot4i(ev.y, pb.y, acc1);
            acc1 = dot4i(ev.z, pb.z, acc1); acc1 = dot4i(ev.w, pb.w, acc1);
        }
        part[0][w * 64 + lane] = acc0;
        part[1][w * 64 + lane] = acc1;
        __syncthreads();

        // ---- epilogue (waves 0/1 in parallel): combine, log, publish ----
        if (w < 2) {
            int s4 = part[w][lane] + part[w][64 + lane]
                   + part[w][128 + lane] + part[w][192 + lane];
            float nv = Cuse - KLOG + __logf((float)s4) + emv;  // log(0) = -inf
            af = (mval > 0.f) ? nv : af;
            publish(W, jblk, (unsigned)t, af, Cnew, lane);
            Cuse = Cnew;
        }
        // next poll's __syncthreads_and protects all LDS reuse
    }

    // ---- log_Z (blocks jblk==0): both batches ----
    if (jblk == 0) {
        if (w < 2 && lane == 0) csh[w] = Cuse;   // barrier below publishes it
        const u64* R0 = xb + ((size_t)((Tn - 1) & 1) * Bn + b0) * XSTR;
        const u64* R1 = xb + ((size_t)((Tn - 1) & 1) * Bn + b1) * XSTR;
        const unsigned tg = (unsigned)(Tn - 1);
        u64 q0 = 0, q1 = 0;
        bool ok = !act;
        while (true) {
            if (!ok) {
                q0 = ald64(R0 + tid);
                q1 = ald64(R1 + tid);
                ok = ((unsigned)(q0 >> 32) == tg) & ((unsigned)(q1 >> 32) == tg);
            }
            if (__syncthreads_and(ok)) break;
        }
        float l0 = 0.f, l1 = 0.f;
        if (act && s17 < 16) {
            unsigned pv0 = (unsigned)q0, pv1 = (unsigned)q1;
            int base = c17 * 64 + s17 * 4;
            l0 = (float)(pv0 & 0xff)         * eteos[base]
               + (float)((pv0 >> 8)  & 0xff) * eteos[base + 1]
               + (float)((pv0 >> 16) & 0xff) * eteos[base + 2]
               + (float)((pv0 >> 24) & 0xff) * eteos[base + 3];
            l1 = (float)(pv1 & 0xff)         * eteos[base]
               + (float)((pv1 >> 8)  & 0xff) * eteos[base + 1]
               + (float)((pv1 >> 16) & 0xff) * eteos[base + 2]
               + (float)((pv1 >> 24) & 0xff) * eteos[base + 3];
        }
        l0 = wave_sum_f(l0);
        l1 = wave_sum_f(l1);
        if (lane == 0) { reds[0][w] = l0; reds[1][w] = l1; }
        __syncthreads();
        if (tid == 0) {
            float t0 = reds[0][0] + reds[0][1] + reds[0][2] + reds[0][3];
            float t1 = reds[1][0] + reds[1][1] + reds[1][2] + reds[1][3];
            float logz0 = csh[0] - KL127 + __logf(t0);
            float logz1 = csh[1] - KL127 + __logf(t1);
            atomicAdd(out, -(scores[b0] - logz0) - (scores[b1] - logz1));
        }
    }
}

extern "C" void kernel_launch(void* const* d_in, const int* in_sizes, int n_in,
                              void* d_out, int out_size, void* d_ws, size_t ws_size,
                              hipStream_t stream) {
    const float* em    = (const float*)d_in[0];
    const int*   tags  = (const int*)d_in[1];
    const float* mask  = (const float*)d_in[2];
    const float* trans = (const float*)d_in[3];
    float* out = (float*)d_out;

    char* ws = (char*)d_ws;
    size_t off = 0;
    unsigned char* eswz = (unsigned char*)(ws + off);
    off += (size_t)ETOT;
    off = (off + 255) & ~(size_t)255;
    float* eteos = (float*)(ws + off); off += JPAD * sizeof(float);
    off = (off + 255) & ~(size_t)255;
    u64* xb = (u64*)(ws + off);        off += (size_t)2 * Bn * XSTR * sizeof(u64);
    off = (off + 255) & ~(size_t)255;
    float* scores = (float*)(ws + off); off += Bn * sizeof(float);

    // ws re-poisoned 0xAA pre-launch: stale tags (0xAAAAAAAA) never match t<128
    (void)hipMemsetAsync(out, 0, sizeof(float), stream);

    build_tabs<<<(ETOT + 255) / 256, 256, 0, stream>>>(trans, eswz, eteos);
    crf_scores<<<Bn, Tn, 0, stream>>>(em, tags, mask, trans, scores);
    crf_fwd<<<dim3(JB, Bn / 2), 256, 0, stream>>>(em, mask, trans, eswz, eteos,
                                                  scores, xb, out);
}

// Round 10
// 391.028 us; speedup vs baseline: 1.0984x; 1.0984x over previous
//
#include <hip/hip_runtime.h>
#include <math.h>

typedef unsigned long long u64;

static constexpr int S    = 771;   // NB_LABELS*MAX_DEPTH + EXTRA
static constexpr int Tn   = 128;
static constexpr int Bn   = 32;
static constexpr int BOSs = 0;
static constexpr int EOSs = 1;

static constexpr int JPAD  = 832;          // 13 * 64 state pad
static constexpr int JB    = 13;           // state-blocks per batch
static constexpr int ROWS  = 64;           // output rows per block (= lanes)
static constexpr int NQ    = 4;            // inner K-quarters (= waves)
static constexpr int SL    = JPAD / NQ;    // 208 i8 inner slice per thread
static constexpr int CH    = SL / 16;      // 13 x b128 per thread
static constexpr int EBLK  = NQ * CH * ROWS * 16;    // 53248 B per jblk
static constexpr int ETOT  = JB * EBLK;              // 692224 B
static constexpr int XSTR  = 224;          // padded stride (u64) per (parity,batch)
static constexpr float CB  = 8.0f;         // normalizer headroom (drift bound)
static constexpr float C0V = 4.5f;         // fixed normalizer for t=0 publish

__device__ __forceinline__ float wave_max_bfly(float v) {   // result in ALL lanes
    #pragma unroll
    for (int off = 32; off > 0; off >>= 1) v = fmaxf(v, __shfl_xor(v, off));
    return v;
}
__device__ __forceinline__ float wave_sum_f(float v) {
    #pragma unroll
    for (int off = 32; off > 0; off >>= 1) v += __shfl_down(v, off);
    return v;
}

__device__ __forceinline__ u64 ald64(const u64* p) {
    return __hip_atomic_load((u64*)p, __ATOMIC_RELAXED, __HIP_MEMORY_SCOPE_AGENT);
}
__device__ __forceinline__ void ast64(u64* p, u64 v) {
    __hip_atomic_store(p, v, __ATOMIC_RELAXED, __HIP_MEMORY_SCOPE_AGENT);
}
__device__ __forceinline__ u64 pack(unsigned tag, unsigned payload) {
    return ((u64)tag << 32) | (u64)payload;
}

// i8 x i8 + i32 dot (both operands in [0,127], so signed == unsigned)
#if __has_builtin(__builtin_amdgcn_sdot4)
__device__ __forceinline__ int dot4i(unsigned a, unsigned b, int c) {
    return __builtin_amdgcn_sdot4((int)a, (int)b, c, false);
}
#else
__device__ __forceinline__ int dot4i(unsigned a, unsigned b, int c) {
    c += (int)(a & 0xff)         * (int)(b & 0xff);
    c += (int)((a >> 8) & 0xff)  * (int)((b >> 8) & 0xff);
    c += (int)((a >> 16) & 0xff) * (int)((b >> 16) & 0xff);
    c += (int)((a >> 24) & 0xff) * (int)((b >> 24) & 0xff);
    return c;
}
#endif

// ---------------------------------------------------------------------------
// Prep: i8 exp-transition table (swizzled, layout unchanged since r8) +
// exp(trans[:,EOS]) f32 column.
// eswz[jblk][q][kk][lane][16] = round(115*exp(trans[i][j])) in [0,127],
//   i = q*208 + kk*16 + e (inner), j = jblk*64 + lane (output row).
// ---------------------------------------------------------------------------
extern "C" __global__ void build_tabs(const float* __restrict__ trans,
                                      unsigned char* __restrict__ eswz,
                                      float* __restrict__ eteos) {
    int idx = blockIdx.x * blockDim.x + threadIdx.x;
    if (idx < JPAD)
        eteos[idx] = (idx < S) ? __expf(trans[idx * S + EOSs]) : 0.f;
    if (idx >= ETOT) return;
    int e = idx & 15;
    int q = idx >> 4;
    int lane = q & 63;  q >>= 6;
    int kk = q % 13;
    int h  = q / 13;
    int w  = h & 3, jblk = h >> 2;
    int i = w * SL + kk * 16 + e;
    int j = jblk * ROWS + lane;
    float v = 0.f;
    if (i < S && j < S) v = 115.f * __expf(trans[i * S + j]);
    int q8 = (int)(v + 0.5f);
    if (q8 > 127) q8 = 127;
    eswz[idx] = (unsigned char)q8;
}

// publish (wave 0): 64 rows -> p8 = round(127*exp(alpha-C)) packed 4/u64
// (16 u64) + 1 u64 f32 chunk max. Tag stream IS the sync.
__device__ __forceinline__ void publish(u64* W, int jblk, unsigned tag,
                                        float af, float C, int lane) {
    float xf = fminf(127.f, 127.f * __expf(af - C));   // -inf/-1e9 -> 0
    int xi = (int)(xf + 0.5f);
    int b0 = __shfl(xi, (4 * lane) & 63);
    int b1 = __shfl(xi, (4 * lane + 1) & 63);
    int b2 = __shfl(xi, (4 * lane + 2) & 63);
    int b3 = __shfl(xi, (4 * lane + 3) & 63);
    unsigned payload = (unsigned)b0 | ((unsigned)b1 << 8)
                     | ((unsigned)b2 << 16) | ((unsigned)b3 << 24);
    float mc = wave_max_bfly(af);
    u64* base = W + 17 * jblk;
    if (lane < 16)  ast64(base + lane, pack(tag, payload));
    if (lane == 16) ast64(base + 16,   pack(tag, __float_as_uint(mc)));
}

// ---------------------------------------------------------------------------
// Forward algorithm, r10: PER-WAVE dataflow sync. Wave w's K-quarter needs
// only publishers bw..bw+3 (bw = 13w/4): 64 data u64 -> ONE load per lane,
// wave-level __any spin, NO block barrier in the poll loop (r9's block-wide
// syncthreads_and poll over all 13 publishers was the dominant cost). Each
// wave writes its 52 u32 to a private LDS strip and reads it back same-wave
// (DS ordering, no barrier). ONE __syncthreads per step (part combine,
// double-buffered by t&1). Wave 0 also polls the 13 chunk maxes for C.
// Safety: block publishes gen t+1 only after all 4 waves (covering all 13
// publishers) passed this step's poll + barrier => transitively every block
// consumed gen t-1 before its parity slot is overwritten (r8 argument).
// Gold-path score computation folded into jblk==0 tail (one fewer launch).
// ---------------------------------------------------------------------------
extern "C" __global__ __launch_bounds__(256, 2)
void crf_fwd(const float* __restrict__ em, const float* __restrict__ mask,
             const float* __restrict__ trans, const int* __restrict__ tags,
             const unsigned char* __restrict__ eswz,
             const float* __restrict__ eteos,
             u64* __restrict__ xb, float* __restrict__ out) {
    const int jblk = blockIdx.x, b = blockIdx.y;
    const int tid = threadIdx.x, lane = tid & 63, w = tid >> 6;
    const int j0 = jblk * ROWS;
    const int bw = (13 * w) / 4;             // 0,3,6,9: first publisher of quarter
    const int lo = 52 * w - 16 * bw;         // 0,4,8,12: lane offset of strip

    __shared__ __align__(16) unsigned char Elds[EBLK];  // 52 KB i8 E tile
    __shared__ __align__(16) unsigned pq[NQ][SL / 4];   // per-wave 52-u32 strip
    __shared__ int   part[2][NQ][ROWS];
    __shared__ float cshare;
    __shared__ float redv[4], redm[4];

    const float KLOG  = __logf(115.f * 127.f);
    const float KL127 = __logf(127.f);

    // ---- one-time: stage this block's E tile (13 x 4KB linear copy) ----
    {
        const unsigned char* gsrc = eswz + (size_t)jblk * EBLK;
        #pragma unroll
        for (int it = 0; it < EBLK / 4096; ++it)
            *(float4*)(Elds + it * 4096 + tid * 16) =
                *(const float4*)(gsrc + it * 4096 + tid * 16);
    }

    // wave-0 per-lane state: alpha of own row + normalizer of consumed gen
    float af = -INFINITY, Cuse = C0V;
    if (w == 0) {
        int j = j0 + lane;
        if (j < S) af = trans[BOSs * S + j] + em[((size_t)b * Tn + 0) * S + j];
        publish(xb + ((size_t)0 * Bn + b) * XSTR, jblk, 0u, af, C0V, lane);
    }

    const bool pollmax = (w == 0) && (lane < JB);

    // ---- 127 sequential steps ----
    for (int t = 1; t < Tn; ++t) {
        const u64* R = xb + ((size_t)((t - 1) & 1) * Bn + b) * XSTR;
        u64*       W = xb + ((size_t)((t    ) & 1) * Bn + b) * XSTR;

        // epilogue operands independent of alpha: issue before the poll
        float emv = 0.f, mval = 0.f;
        if (w == 0) {
            const int j = j0 + lane;
            if (j < S) emv = em[((size_t)b * Tn + t) * S + j];
            mval = mask[b * Tn + t];
        }

        // ---- per-wave poll: one data u64/lane (+ maxes on wave 0) ----
        const unsigned tg = (unsigned)(t - 1);
        const u64* pd = R + 17 * (bw + (lane >> 4)) + (lane & 15);
        const u64* pm = R + 17 * lane + 16;
        u64 qd = 0, qm = 0;
        bool okd = false, okm = !pollmax;
        do {
            if (!okd) { qd = ald64(pd); okd = ((unsigned)(qd >> 32) == tg); }
            if (!okm) { qm = ald64(pm); okm = ((unsigned)(qm >> 32) == tg); }
        } while (__any((!okd) | (!okm)));

        // ---- unpack own strip (same-wave write->read: DS order, no barrier)
        if (lane >= lo && lane < lo + 52) pq[w][lane - lo] = (unsigned)qd;

        // wave 0: next normalizer from the 13 chunk maxes
        float Cnew = 0.f;
        if (w == 0) {
            float mv = (lane < JB) ? __uint_as_float((unsigned)qm) : -INFINITY;
            Cnew = wave_max_bfly(mv) + CB;
        }

        // ---- dot: LDS i8 E (b128) x own strip (b128 broadcast) ----
        int acc = 0;
        const uint4* E4 = (const uint4*)Elds;
        const uint4* P4 = (const uint4*)pq[w];
        #pragma unroll
        for (int kk = 0; kk < CH; ++kk) {
            const uint4 ev = E4[(w * CH + kk) * 64 + lane];
            const uint4 pv = P4[kk];
            acc = dot4i(ev.x, pv.x, acc);
            acc = dot4i(ev.y, pv.y, acc);
            acc = dot4i(ev.z, pv.z, acc);
            acc = dot4i(ev.w, pv.w, acc);
        }
        part[t & 1][w][lane] = acc;
        __syncthreads();   // the ONLY per-step barrier

        // ---- epilogue (wave 0): combine, log, publish gen t ----
        if (w == 0) {
            int s4 = part[t & 1][0][lane] + part[t & 1][1][lane]
                   + part[t & 1][2][lane] + part[t & 1][3][lane];
            float nv = Cuse - KLOG + __logf((float)s4) + emv;  // log(0) = -inf
            af = (mval > 0.f) ? nv : af;
            publish(W, jblk, (unsigned)t, af, Cnew, lane);
            if (lane == 0) cshare = Cnew;
            Cuse = Cnew;
        }
    }

    // ---- tail (block jblk==0 only): log_Z + gold score + output ----
    if (jblk == 0) {
        // full-block one-time poll of gen 127 data (208 u64)
        const u64* R = xb + ((size_t)((Tn - 1) & 1) * Bn + b) * XSTR;
        const unsigned tg = (unsigned)(Tn - 1);
        const bool act = (tid < JB * 16);
        u64 q = 0;
        bool ok = !act;
        while (true) {
            if (!ok) {
                q = ald64(R + 17 * (tid >> 4) + (tid & 15));
                ok = ((unsigned)(q >> 32) == tg);
            }
            if (__syncthreads_and(ok)) break;
        }
        float lsum = 0.f;
        if (act) {
            unsigned pv = (unsigned)q;
            int base = 4 * tid;                 // p8 index = (j*64 + s*4)
            lsum = (float)(pv & 0xff)         * eteos[base]
                 + (float)((pv >> 8)  & 0xff) * eteos[base + 1]
                 + (float)((pv >> 16) & 0xff) * eteos[base + 2]
                 + (float)((pv >> 24) & 0xff) * eteos[base + 3];
        }
        // gold-path score (inlined crf_scores): thread tid<128 handles pos tid
        float mk = 0.f, val = 0.f;
        if (tid < Tn) {
            mk = mask[b * Tn + tid];
            if (tid > 0) {
                int cur  = tags[b * Tn + tid];
                int prev = tags[b * Tn + tid - 1];
                val = (em[((size_t)b * Tn + tid) * S + cur]
                       + trans[prev * S + cur]) * mk;
            }
        }
        lsum = wave_sum_f(lsum);
        float vs = wave_sum_f(val);
        float ms = wave_sum_f(mk);
        if (lane == 0) { redv[w] = vs; redm[w] = ms; part[0][0][w] = 0; }
        if (lane == 1) part[1][0][w] = __float_as_int(lsum);
        __syncthreads();
        if (tid == 0) {
            float tot = __int_as_float(part[1][0][0]) + __int_as_float(part[1][0][1])
                      + __int_as_float(part[1][0][2]) + __int_as_float(part[1][0][3]);
            float logz = cshare - KL127 + __logf(tot);
            float msum = redm[0] + redm[1] + redm[2] + redm[3];
            int last   = (int)(msum + 0.5f) - 1;
            int first  = tags[b * Tn];
            int lastt  = tags[b * Tn + last];
            float score = redv[0] + redv[1] + redv[2] + redv[3]
                        + trans[BOSs * S + first]
                        + em[((size_t)b * Tn) * S + first]
                        + trans[lastt * S + EOSs];
            atomicAdd(out, -(score - logz));
        }
    }
}

extern "C" void kernel_launch(void* const* d_in, const int* in_sizes, int n_in,
                              void* d_out, int out_size, void* d_ws, size_t ws_size,
                              hipStream_t stream) {
    const float* em    = (const float*)d_in[0];
    const int*   tags  = (const int*)d_in[1];
    const float* mask  = (const float*)d_in[2];
    const float* trans = (const float*)d_in[3];
    float* out = (float*)d_out;

    char* ws = (char*)d_ws;
    size_t off = 0;
    unsigned char* eswz = (unsigned char*)(ws + off);
    off += (size_t)ETOT;
    off = (off + 255) & ~(size_t)255;
    float* eteos = (float*)(ws + off); off += JPAD * sizeof(float);
    off = (off + 255) & ~(size_t)255;
    u64* xb = (u64*)(ws + off);        off += (size_t)2 * Bn * XSTR * sizeof(u64);

    // ws re-poisoned 0xAA pre-launch: stale tags (0xAAAAAAAA) never match t<128
    (void)hipMemsetAsync(out, 0, sizeof(float), stream);

    build_tabs<<<(ETOT + 255) / 256, 256, 0, stream>>>(trans, eswz, eteos);
    crf_fwd<<<dim3(JB, Bn), 256, 0, stream>>>(em, mask, trans, tags, eswz,
                                              eteos, xb, out);
}